// Round 5
// baseline (1893.910 us; speedup 1.0000x reference)
//
#include <hip/hip_runtime.h>

#define N_JOB 500000
#define N_WORKER 50000
#define E_PRE 4000000
#define E_NXT 4000000
#define E_PROC 2000000
#define BASE_NXT E_PRE
#define BASE_PROC (E_PRE + E_NXT)
#define EHALF 2000000              // E_PRE/2 == E_NXT/2 == E_PROC

#define SCAN_N (3 * N_JOB)         // concatenated in-degrees: [in_pre | in_nxt | in_proc]
#define SCAN_BLK 2048              // 256 threads * 8 elems
#define SCAN_NB ((SCAN_N + SCAN_BLK - 1) / SCAN_BLK)   // 733 (must be <= 1024)

#define KWIN 4                     // placement windows
#define WIN_SZ ((N_JOB + KWIN - 1) / KWIN)             // 125000

#define NTL(p) __builtin_nontemporal_load(p)

// ---------------------------------------------------------------------------
// Degree counting, single pass, nt index loads (streams don't evict the
// ~10MB counter set from L2). deg layout (5*N_JOB ints):
//   [0]=in_pre  [1]=in_nxt  [2]=in_proc  [3]=out_pre  [4]=out_nxt
// ---------------------------------------------------------------------------
__global__ void degrees_all(const int* __restrict__ pre_src, const int* __restrict__ pre_dst,
                            const int* __restrict__ nxt_src, const int* __restrict__ nxt_dst,
                            const int* __restrict__ proc_dst, int* __restrict__ deg) {
    int i = blockIdx.x * blockDim.x + threadIdx.x;
    if (i >= EHALF) return;
#pragma unroll
    for (int j = 0; j < 2; ++j) {
        int k = i + j * EHALF;
        int d0 = NTL(pre_dst + k), s0 = NTL(pre_src + k);
        int d1 = NTL(nxt_dst + k), s1 = NTL(nxt_src + k);
        atomicAdd(&deg[0 * N_JOB + d0], 1);
        atomicAdd(&deg[3 * N_JOB + s0], 1);
        atomicAdd(&deg[1 * N_JOB + d1], 1);
        atomicAdd(&deg[4 * N_JOB + s1], 1);
    }
    int dp = NTL(proc_dst + i);
    atomicAdd(&deg[2 * N_JOB + dp], 1);
}

// Convert out-degree ints (segments 3,4) -> rsqrt floats in place.
__global__ void convert_out(float* __restrict__ base) {
    int i = blockIdx.x * blockDim.x + threadIdx.x;
    if (i >= 2 * N_JOB) return;
    int d = ((const int*)base)[i];
    base[i] = rsqrtf((float)(d < 1 ? 1 : d));
}

// ---------------------------------------------------------------------------
// Exclusive scan over SCAN_N ints (3-kernel two-level scan).
// ---------------------------------------------------------------------------
__global__ void scan_blocksum(const int* __restrict__ in, int* __restrict__ bsum, int n) {
    __shared__ int sd[256];
    int t = threadIdx.x;
    int base = blockIdx.x * SCAN_BLK + t * 8;
    int sum = 0;
#pragma unroll
    for (int j = 0; j < 8; ++j) {
        int idx = base + j;
        if (idx < n) sum += in[idx];
    }
    sd[t] = sum;
    __syncthreads();
    for (int o = 128; o > 0; o >>= 1) {
        if (t < o) sd[t] += sd[t + o];
        __syncthreads();
    }
    if (t == 0) bsum[blockIdx.x] = sd[0];
}

__global__ void scan_bsum(int* __restrict__ bsum, int nb) {
    __shared__ int s[1024];
    int t = threadIdx.x;
    int orig = (t < nb) ? bsum[t] : 0;
    s[t] = orig;
    __syncthreads();
    for (int o = 1; o < 1024; o <<= 1) {
        int v = (t >= o) ? s[t - o] : 0;
        __syncthreads();
        s[t] += v;
        __syncthreads();
    }
    if (t < nb) bsum[t] = s[t] - orig;  // exclusive
}

__global__ void scan_final(const int* __restrict__ in, const int* __restrict__ bsum,
                           int* __restrict__ off, int n) {
    __shared__ int sd[256];
    int t = threadIdx.x;
    int base = blockIdx.x * SCAN_BLK + t * 8;
    int vals[8];
    int tsum = 0;
#pragma unroll
    for (int j = 0; j < 8; ++j) {
        int idx = base + j;
        vals[j] = (idx < n) ? in[idx] : 0;
        tsum += vals[j];
    }
    sd[t] = tsum;
    __syncthreads();
    for (int o = 1; o < 256; o <<= 1) {
        int v = (t >= o) ? sd[t - o] : 0;
        __syncthreads();
        sd[t] += v;
        __syncthreads();
    }
    int run = bsum[blockIdx.x] + sd[t] - tsum;  // block base + exclusive thread prefix
#pragma unroll
    for (int j = 0; j < 8; ++j) {
        int idx = base + j;
        if (idx < n) off[idx] = run;
        run += vals[j];
    }
}

// ---------------------------------------------------------------------------
// Windowed CSR placement, nt index loads, ILP: 2 pre + 2 nxt + 1 proc edge
// per thread. off holds global edge ids: pre [0,4M), nxt [4M,8M), proc
// [8M,10M). adj_jj gets src for pre/nxt; adj_proc gets (src, edge_id).
// ---------------------------------------------------------------------------
__global__ void placement_win2(const int* __restrict__ pre_src, const int* __restrict__ pre_dst,
                               const int* __restrict__ nxt_src, const int* __restrict__ nxt_dst,
                               const int* __restrict__ proc_src, const int* __restrict__ proc_dst,
                               int* __restrict__ off, int* __restrict__ adj_jj,
                               int2* __restrict__ adj_proc, int wlo, int whi) {
    int i = blockIdx.x * blockDim.x + threadIdx.x;
    if (i >= EHALF) return;
#pragma unroll
    for (int j = 0; j < 2; ++j) {
        int k = i + j * EHALF;
        int d0 = NTL(pre_dst + k);
        if (d0 >= wlo && d0 < whi) {
            int p = atomicAdd(&off[0 * N_JOB + d0], 1);
            adj_jj[p] = NTL(pre_src + k);
        }
        int d1 = NTL(nxt_dst + k);
        if (d1 >= wlo && d1 < whi) {
            int p = atomicAdd(&off[1 * N_JOB + d1], 1);
            adj_jj[p] = NTL(nxt_src + k);
        }
    }
    int dp = NTL(proc_dst + i);
    if (dp >= wlo && dp < whi) {
        int p = atomicAdd(&off[2 * N_JOB + dp], 1);
        adj_proc[p - BASE_PROC] = make_int2(NTL(proc_src + i), i);
    }
}

// ---------------------------------------------------------------------------
// Embedding: one thread per row, weights staged in LDS.
// ---------------------------------------------------------------------------
template <int F>
__global__ void embed_kernel(const float* __restrict__ feat, const float* __restrict__ W,
                             const float* __restrict__ b, float* __restrict__ out, int n) {
    __shared__ float Ws[F * 16];
    __shared__ float bs[16];
    int t = threadIdx.x;
    if (t < F * 16) Ws[t] = W[t];
    if (t < 16) bs[t] = b[t];
    __syncthreads();
    int i = blockIdx.x * blockDim.x + t;
    if (i >= n) return;
    float f[F];
#pragma unroll
    for (int k = 0; k < F; k++) f[k] = feat[(size_t)i * F + k];
    float o[16];
#pragma unroll
    for (int d = 0; d < 16; d++) {
        float s = bs[d];
#pragma unroll
        for (int k = 0; k < F; k++) s += f[k] * Ws[k * 16 + d];
        o[d] = s;
    }
    float4* dst4 = (float4*)(out + (size_t)i * 16);
    dst4[0] = make_float4(o[0], o[1], o[2], o[3]);
    dst4[1] = make_float4(o[4], o[5], o[6], o[7]);
    dst4[2] = make_float4(o[8], o[9], o[10], o[11]);
    dst4[3] = make_float4(o[12], o[13], o[14], o[15]);
}

// ---------------------------------------------------------------------------
// Merged per-layer gather: pre-conv + nxt-conv + sage(mean) + self, one kernel.
// 4 lanes per node; lane c owns float4 chunk c. In-degree normalizers come
// from row lengths. adj streams are nt-loaded so they don't evict h-rows from
// L2. FINAL also computes the dot-product readout using the just-computed hj
// chunk against L2-warm hw rows (adj_proc carries edge ids).
// ---------------------------------------------------------------------------
__device__ __forceinline__ void mm_accum(const float* __restrict__ Ws, float4 a, int c, float o[4]) {
#pragma unroll
    for (int g = 0; g < 4; ++g) {
        float a0 = __shfl(a.x, g, 4);
        float a1 = __shfl(a.y, g, 4);
        float a2 = __shfl(a.z, g, 4);
        float a3 = __shfl(a.w, g, 4);
        const float* wr = &Ws[(4 * g) * 16 + c * 4];
#pragma unroll
        for (int j = 0; j < 4; ++j)
            o[j] += a0 * wr[j] + a1 * wr[16 + j] + a2 * wr[32 + j] + a3 * wr[48 + j];
    }
}

template <bool FINAL>
__global__ void gather_layer(const float* __restrict__ cur, const float* __restrict__ hwk,
                             const int* __restrict__ adj_jj, const int2* __restrict__ adj_proc,
                             const int* __restrict__ off,
                             const float* __restrict__ sc_pre, const float* __restrict__ sc_nxt,
                             const float* __restrict__ Wp, const float* __restrict__ Wn,
                             const float* __restrict__ Wng, const float* __restrict__ Wsf,
                             const float* __restrict__ bp, const float* __restrict__ bn,
                             const float* __restrict__ bsg,
                             float* __restrict__ out, float* __restrict__ scores) {
    __shared__ float WpS[256], WnS[256], WngS[256], WsfS[256], bs[16];
    int t = threadIdx.x;
    WpS[t] = Wp[t]; WnS[t] = Wn[t]; WngS[t] = Wng[t]; WsfS[t] = Wsf[t];
    if (t < 16) bs[t] = bp[t] + bn[t] + bsg[t];
    __syncthreads();
    unsigned gid = blockIdx.x * 256 + t;
    unsigned v = gid >> 2, c = gid & 3;
    if (v >= N_JOB) return;
    const int* rend0 = off;
    const int* rend1 = off + N_JOB;
    const int* rend2 = off + 2 * N_JOB;
    int e0 = rend0[v], s0 = v ? rend0[v - 1] : 0;
    int e1 = rend1[v], s1 = v ? rend1[v - 1] : BASE_NXT;
    int e2 = rend2[v] - BASE_PROC;
    int s2 = (v ? rend2[v - 1] : BASE_PROC) - BASE_PROC;

    // precede-conv aggregation (scaled by rsqrt(out_deg) of src)
    float4 accP = make_float4(0.f, 0.f, 0.f, 0.f);
    {
        int p = s0;
        for (; p + 1 < e0; p += 2) {
            int sa = NTL(adj_jj + p), sb = NTL(adj_jj + p + 1);
            float wa = sc_pre[sa], wb = sc_pre[sb];
            float4 ha = ((const float4*)(cur + (size_t)sa * 16))[c];
            float4 hb = ((const float4*)(cur + (size_t)sb * 16))[c];
            accP.x += ha.x * wa + hb.x * wb; accP.y += ha.y * wa + hb.y * wb;
            accP.z += ha.z * wa + hb.z * wb; accP.w += ha.w * wa + hb.w * wb;
        }
        if (p < e0) {
            int sa = NTL(adj_jj + p);
            float wa = sc_pre[sa];
            float4 ha = ((const float4*)(cur + (size_t)sa * 16))[c];
            accP.x += ha.x * wa; accP.y += ha.y * wa; accP.z += ha.z * wa; accP.w += ha.w * wa;
        }
    }
    // next-conv aggregation
    float4 accN = make_float4(0.f, 0.f, 0.f, 0.f);
    {
        int p = s1;
        for (; p + 1 < e1; p += 2) {
            int sa = NTL(adj_jj + p), sb = NTL(adj_jj + p + 1);
            float wa = sc_nxt[sa], wb = sc_nxt[sb];
            float4 ha = ((const float4*)(cur + (size_t)sa * 16))[c];
            float4 hb = ((const float4*)(cur + (size_t)sb * 16))[c];
            accN.x += ha.x * wa + hb.x * wb; accN.y += ha.y * wa + hb.y * wb;
            accN.z += ha.z * wa + hb.z * wb; accN.w += ha.w * wa + hb.w * wb;
        }
        if (p < e1) {
            int sa = NTL(adj_jj + p);
            float wa = sc_nxt[sa];
            float4 ha = ((const float4*)(cur + (size_t)sa * 16))[c];
            accN.x += ha.x * wa; accN.y += ha.y * wa; accN.z += ha.z * wa; accN.w += ha.w * wa;
        }
    }
    // sage mean aggregation over worker neighbors (hw is small, L2-resident)
    float4 accS = make_float4(0.f, 0.f, 0.f, 0.f);
    {
        int p = s2;
        for (; p + 1 < e2; p += 2) {
            long long pva = NTL((const long long*)(adj_proc + p));
            long long pvb = NTL((const long long*)(adj_proc + p + 1));
            int sa = (int)pva, sb = (int)pvb;
            float4 ha = ((const float4*)(hwk + (size_t)sa * 16))[c];
            float4 hb = ((const float4*)(hwk + (size_t)sb * 16))[c];
            accS.x += ha.x + hb.x; accS.y += ha.y + hb.y;
            accS.z += ha.z + hb.z; accS.w += ha.w + hb.w;
        }
        if (p < e2) {
            long long pva = NTL((const long long*)(adj_proc + p));
            int sa = (int)pva;
            float4 ha = ((const float4*)(hwk + (size_t)sa * 16))[c];
            accS.x += ha.x; accS.y += ha.y; accS.z += ha.z; accS.w += ha.w;
        }
    }

    int d0 = e0 - s0, d1 = e1 - s1, d2 = e2 - s2;
    float rp = rsqrtf((float)(d0 < 1 ? 1 : d0));
    float rn = rsqrtf((float)(d1 < 1 ? 1 : d1));
    float ri = 1.0f / (float)(d2 < 1 ? 1 : d2);
    accP.x *= rp; accP.y *= rp; accP.z *= rp; accP.w *= rp;
    accN.x *= rn; accN.y *= rn; accN.z *= rn; accN.w *= rn;
    accS.x *= ri; accS.y *= ri; accS.z *= ri; accS.w *= ri;

    float o[4];
#pragma unroll
    for (int j = 0; j < 4; ++j) o[j] = bs[c * 4 + j];
    mm_accum(WpS, accP, c, o);
    mm_accum(WnS, accN, c, o);
    mm_accum(WngS, accS, c, o);
    float4 hself = ((const float4*)(cur + (size_t)v * 16))[c];
    mm_accum(WsfS, hself, c, o);
    ((float4*)(out + (size_t)v * 16))[c] = make_float4(o[0], o[1], o[2], o[3]);

    if (FINAL) {
        // readout: dot(hw[u], hj_new[v]) per proc edge, hw rows are L2-warm
        for (int p = s2; p < e2; ++p) {
            int2 pr = adj_proc[p];
            float4 wv = ((const float4*)(hwk + (size_t)pr.x * 16))[c];
            float d = o[0] * wv.x + o[1] * wv.y + o[2] * wv.z + o[3] * wv.w;
            d += __shfl_xor(d, 1, 4);
            d += __shfl_xor(d, 2, 4);
            if (c == 0) scores[pr.y] = d;
        }
    }
}

extern "C" void kernel_launch(void* const* d_in, const int* in_sizes, int n_in,
                              void* d_out, int out_size, void* d_ws, size_t ws_size,
                              hipStream_t stream) {
    const float* job_feat     = (const float*)d_in[0];
    const float* worker_feat  = (const float*)d_in[1];
    const int*   pre_src      = (const int*)d_in[2];
    const int*   pre_dst      = (const int*)d_in[3];
    const int*   nxt_src      = (const int*)d_in[4];
    const int*   nxt_dst      = (const int*)d_in[5];
    const int*   proc_src     = (const int*)d_in[6];
    const int*   proc_dst     = (const int*)d_in[7];
    const float* W_emb_job    = (const float*)d_in[8];
    const float* b_emb_job    = (const float*)d_in[9];
    const float* W_emb_worker = (const float*)d_in[10];
    const float* b_emb_worker = (const float*)d_in[11];
    const float* W_pre        = (const float*)d_in[12];
    const float* b_pre        = (const float*)d_in[13];
    const float* W_nxt        = (const float*)d_in[14];
    const float* b_nxt        = (const float*)d_in[15];
    const float* W_self       = (const float*)d_in[16];
    const float* W_neigh      = (const float*)d_in[17];
    const float* b_sage       = (const float*)d_in[18];
    float* out = (float*)d_out;

    // Workspace layout (ints/floats), ~131 MB total
    float* ws   = (float*)d_ws;
    float* hjA  = ws;                                   // 8,000,000 f
    float* hjB  = hjA + (size_t)N_JOB * 16;             // 8,000,000 f
    float* hw   = hjB + (size_t)N_JOB * 16;             //   800,000 f
    float* rs   = hw + (size_t)N_WORKER * 16;           // 2,500,000 (deg ints -> norm floats)
    int*   off  = (int*)(rs + (size_t)5 * N_JOB);       // 1,500,000 (row offsets -> ends)
    int*   bsum = off + SCAN_N;                         // 1024
    int*   adj_jj = bsum + 1024;                        // 8,000,000
    int2*  adj_proc = (int2*)(adj_jj + (size_t)(E_PRE + E_NXT)); // 2,000,000 int2

    float* sc_pre = rs + 3 * (size_t)N_JOB;             // rsqrt(out_deg) pre
    float* sc_nxt = rs + 4 * (size_t)N_JOB;             // rsqrt(out_deg) nxt

    hipMemsetAsync(rs, 0, (size_t)5 * N_JOB * sizeof(float), stream);

    const int HGRID = (EHALF + 255) / 256;

    // Degree counting: single pass, nt index loads keep counters L2-hot.
    degrees_all<<<HGRID, 256, 0, stream>>>(
        pre_src, pre_dst, nxt_src, nxt_dst, proc_dst, (int*)rs);

    // CSR row offsets from concatenated in-degrees.
    scan_blocksum<<<SCAN_NB, 256, 0, stream>>>((const int*)rs, bsum, SCAN_N);
    scan_bsum<<<1, 1024, 0, stream>>>(bsum, SCAN_NB);
    scan_final<<<SCAN_NB, 256, 0, stream>>>((const int*)rs, bsum, off, SCAN_N);

    // Out-degree normalizers (segments 3,4 only; in-degs come from row lengths).
    convert_out<<<(2 * N_JOB + 255) / 256, 256, 0, stream>>>(rs + 3 * (size_t)N_JOB);

    // Windowed placement with ILP + nt index loads.
    for (int w = 0; w < KWIN; ++w) {
        int wlo = w * WIN_SZ;
        int whi = (wlo + WIN_SZ < N_JOB) ? wlo + WIN_SZ : N_JOB;
        placement_win2<<<HGRID, 256, 0, stream>>>(
            pre_src, pre_dst, nxt_src, nxt_dst, proc_src, proc_dst,
            off, adj_jj, adj_proc, wlo, whi);
    }

    embed_kernel<7><<<(N_JOB + 255) / 256, 256, 0, stream>>>(job_feat, W_emb_job, b_emb_job, hjA, N_JOB);
    embed_kernel<3><<<(N_WORKER + 255) / 256, 256, 0, stream>>>(worker_feat, W_emb_worker, b_emb_worker, hw, N_WORKER);

    const int GGRID = (4 * N_JOB + 255) / 256;
    gather_layer<false><<<GGRID, 256, 0, stream>>>(
        hjA, hw, adj_jj, adj_proc, off, sc_pre, sc_nxt,
        W_pre, W_nxt, W_neigh, W_self, b_pre, b_nxt, b_sage, hjB, nullptr);
    gather_layer<true><<<GGRID, 256, 0, stream>>>(
        hjB, hw, adj_jj, adj_proc, off, sc_pre, sc_nxt,
        W_pre, W_nxt, W_neigh, W_self, b_pre, b_nxt, b_sage, hjA, out);
}

// Round 6
// 1804.966 us; speedup vs baseline: 1.0493x; 1.0493x over previous
//
#include <hip/hip_runtime.h>

#define N_JOB 500000
#define N_WORKER 50000
#define E_PRE 4000000
#define E_NXT 4000000
#define E_PROC 2000000
#define E_TOT 10000000
#define BASE_NXT E_PRE
#define BASE_PROC (E_PRE + E_NXT)

#define SCAN_N (3 * N_JOB)         // concatenated in-degrees: [in_pre | in_nxt | in_proc]
#define SCAN_BLK 2048              // 256 threads * 8 elems
#define SCAN_NB ((SCAN_N + SCAN_BLK - 1) / SCAN_BLK)   // 733 (must be <= 1024)

// dst-window partition: 64 windows x 8192 nodes; 192 segments total
// (rel0 w=0..63 | rel1 64..127 | proc 128..191)
#define WBITS 13
#define WSZ 8192
#define NWIN 64
#define NSEG 192
#define CAP_JJ 68000               // mean 65536 + 9.7 sigma
#define CAP_PR 34000               // mean 32768 + 6.8 sigma
#define BPW 128                    // chunks per window in bucket passes

// ---------------------------------------------------------------------------
// Per-call cursor init: segment bases into the bucket arrays.
// ---------------------------------------------------------------------------
__global__ void cursor_init(int* __restrict__ gcursor) {
    int t = threadIdx.x;
    if (t < NSEG) gcursor[t] = (t < 128) ? t * CAP_JJ : (t - 128) * CAP_PR;
}

// ---------------------------------------------------------------------------
// Partition: single streaming read of all edges; LDS histogram over 192
// (rel,window) segments; one global atomicAdd per segment per block to
// reserve; replay from registers into bucket slots.
// jj entry: (dst&8191)<<19 | src (src < 2^19). proc entry: int2{(dl<<16)|src, eid}.
// ---------------------------------------------------------------------------
__global__ void partition_kernel(const int* __restrict__ pre_src, const int* __restrict__ pre_dst,
                                 const int* __restrict__ nxt_src, const int* __restrict__ nxt_dst,
                                 const int* __restrict__ proc_src, const int* __restrict__ proc_dst,
                                 int* __restrict__ gcursor,
                                 unsigned* __restrict__ jjb, int2* __restrict__ procb) {
    __shared__ int cnt[NSEG];
    __shared__ int lbase[NSEG];
    int t = threadIdx.x;
    if (t < NSEG) cnt[t] = 0;
    __syncthreads();
    int base = blockIdx.x * 2048;
    int mykey[8], myidx[8], myeid[8];
#pragma unroll
    for (int j = 0; j < 8; ++j) {
        int id = base + t + j * 256;
        int idx = -1, key = 0, eid = 0;
        if (id < E_TOT) {
            int d, s;
            if (id < BASE_NXT) {
                d = pre_dst[id]; s = pre_src[id];
                idx = (d >> WBITS); key = ((d & (WSZ - 1)) << 19) | s;
            } else if (id < BASE_PROC) {
                int q = id - BASE_NXT;
                d = nxt_dst[q]; s = nxt_src[q];
                idx = 64 + (d >> WBITS); key = ((d & (WSZ - 1)) << 19) | s;
            } else {
                int q = id - BASE_PROC;
                d = proc_dst[q]; s = proc_src[q];
                idx = 128 + (d >> WBITS); key = ((d & (WSZ - 1)) << 16) | s; eid = q;
            }
            atomicAdd(&cnt[idx], 1);
        }
        mykey[j] = key; myidx[j] = idx; myeid[j] = eid;
    }
    __syncthreads();
    if (t < NSEG) {
        int c = cnt[t];
        lbase[t] = c ? atomicAdd(&gcursor[t], c) : 0;
    }
    __syncthreads();
    if (t < NSEG) cnt[t] = 0;   // reuse as local cursor
    __syncthreads();
#pragma unroll
    for (int j = 0; j < 8; ++j) {
        int idx = myidx[j];
        if (idx < 0) continue;
        int slot = lbase[idx] + atomicAdd(&cnt[idx], 1);
        if (idx < 128) jjb[slot] = (unsigned)mykey[j];
        else           procb[slot] = make_int2(mykey[j], myeid[j]);
    }
}

// ---------------------------------------------------------------------------
// Bucket passes: grid is XCD-pinned window-major (blockIdx%8 = xcd owns
// windows w = xcd, xcd+8, ...), BPW chunks per window, so each XCD's L2 holds
// only ~1-2 windows' counters/adj regions (~0.1-1.5 MB) at a time.
// PLACE=false: count in-degrees into deg. PLACE=true: scatter into adj via
// off cursors (off becomes row ENDS).
// ---------------------------------------------------------------------------
template <bool PLACE>
__global__ void bucket_pass(const unsigned* __restrict__ jjb, const int2* __restrict__ procb,
                            const int* __restrict__ gcursor, int* __restrict__ deg_off,
                            int* __restrict__ adj_jj, int2* __restrict__ adj_proc) {
    int xcd = blockIdx.x & 7;
    int k = blockIdx.x >> 3;
    int w = ((k >> 7) << 3) + xcd;       // 8 windows per xcd, in order
    int chunk = k & (BPW - 1);
    int t = threadIdx.x;
    int wlo = w << WBITS;
#pragma unroll
    for (int rel = 0; rel < 2; ++rel) {
        int idx = rel * 64 + w;
        int start = idx * CAP_JJ;
        int end = gcursor[idx];
        int cnt = end - start;
        int clen = (cnt + BPW - 1) >> 7;
        int sb = start + chunk * clen;
        int se = sb + clen; if (se > end) se = end;
        int* degp = deg_off + rel * N_JOB;
        for (int p = sb + t; p < se; p += 256) {
            unsigned e = jjb[p];
            int dst = wlo + (int)(e >> 19);
            if (PLACE) {
                int pos = atomicAdd(&degp[dst], 1);
                adj_jj[pos] = (int)(e & 0x7FFFFu);
            } else {
                atomicAdd(&degp[dst], 1);
            }
        }
    }
    {
        int idx = 128 + w;
        int start = (idx - 128) * CAP_PR;
        int end = gcursor[idx];
        int cnt = end - start;
        int clen = (cnt + BPW - 1) >> 7;
        int sb = start + chunk * clen;
        int se = sb + clen; if (se > end) se = end;
        int* degp = deg_off + 2 * N_JOB;
        for (int p = sb + t; p < se; p += 256) {
            int2 e = procb[p];
            int dst = wlo + (e.x >> 16);
            if (PLACE) {
                int pos = atomicAdd(&degp[dst], 1);
                adj_proc[pos - BASE_PROC] = make_int2(e.x & 0xFFFF, e.y);
            } else {
                atomicAdd(&degp[dst], 1);
            }
        }
    }
}

// ---------------------------------------------------------------------------
// Out-degree histogram (keyed by src, can't use dst buckets): 4 windowed
// passes, hot set 2 segs x 0.5 MB = 1 MB per pass (proven-fast regime).
// ---------------------------------------------------------------------------
__global__ void outdeg_win(const int* __restrict__ pre_src, const int* __restrict__ nxt_src,
                           int* __restrict__ deg, int wlo, int whi) {
    int base = blockIdx.x * 1024;
    int t = threadIdx.x;
#pragma unroll
    for (int j = 0; j < 4; ++j) {
        int i = base + t + j * 256;
        if (i < E_PRE) {
            int s0 = pre_src[i];
            if (s0 >= wlo && s0 < whi) atomicAdd(&deg[3 * N_JOB + s0], 1);
            int s1 = nxt_src[i];
            if (s1 >= wlo && s1 < whi) atomicAdd(&deg[4 * N_JOB + s1], 1);
        }
    }
}

// Convert out-degree ints (segments 3,4) -> rsqrt floats in place.
__global__ void convert_out(float* __restrict__ base) {
    int i = blockIdx.x * blockDim.x + threadIdx.x;
    if (i >= 2 * N_JOB) return;
    int d = ((const int*)base)[i];
    base[i] = rsqrtf((float)(d < 1 ? 1 : d));
}

// ---------------------------------------------------------------------------
// Exclusive scan over SCAN_N ints (3-kernel two-level scan).
// ---------------------------------------------------------------------------
__global__ void scan_blocksum(const int* __restrict__ in, int* __restrict__ bsum, int n) {
    __shared__ int sd[256];
    int t = threadIdx.x;
    int base = blockIdx.x * SCAN_BLK + t * 8;
    int sum = 0;
#pragma unroll
    for (int j = 0; j < 8; ++j) {
        int idx = base + j;
        if (idx < n) sum += in[idx];
    }
    sd[t] = sum;
    __syncthreads();
    for (int o = 128; o > 0; o >>= 1) {
        if (t < o) sd[t] += sd[t + o];
        __syncthreads();
    }
    if (t == 0) bsum[blockIdx.x] = sd[0];
}

__global__ void scan_bsum(int* __restrict__ bsum, int nb) {
    __shared__ int s[1024];
    int t = threadIdx.x;
    int orig = (t < nb) ? bsum[t] : 0;
    s[t] = orig;
    __syncthreads();
    for (int o = 1; o < 1024; o <<= 1) {
        int v = (t >= o) ? s[t - o] : 0;
        __syncthreads();
        s[t] += v;
        __syncthreads();
    }
    if (t < nb) bsum[t] = s[t] - orig;  // exclusive
}

__global__ void scan_final(const int* __restrict__ in, const int* __restrict__ bsum,
                           int* __restrict__ off, int n) {
    __shared__ int sd[256];
    int t = threadIdx.x;
    int base = blockIdx.x * SCAN_BLK + t * 8;
    int vals[8];
    int tsum = 0;
#pragma unroll
    for (int j = 0; j < 8; ++j) {
        int idx = base + j;
        vals[j] = (idx < n) ? in[idx] : 0;
        tsum += vals[j];
    }
    sd[t] = tsum;
    __syncthreads();
    for (int o = 1; o < 256; o <<= 1) {
        int v = (t >= o) ? sd[t - o] : 0;
        __syncthreads();
        sd[t] += v;
        __syncthreads();
    }
    int run = bsum[blockIdx.x] + sd[t] - tsum;
#pragma unroll
    for (int j = 0; j < 8; ++j) {
        int idx = base + j;
        if (idx < n) off[idx] = run;
        run += vals[j];
    }
}

// ---------------------------------------------------------------------------
// Embedding: one thread per row, weights staged in LDS.
// ---------------------------------------------------------------------------
template <int F>
__global__ void embed_kernel(const float* __restrict__ feat, const float* __restrict__ W,
                             const float* __restrict__ b, float* __restrict__ out, int n) {
    __shared__ float Ws[F * 16];
    __shared__ float bs[16];
    int t = threadIdx.x;
    if (t < F * 16) Ws[t] = W[t];
    if (t < 16) bs[t] = b[t];
    __syncthreads();
    int i = blockIdx.x * blockDim.x + t;
    if (i >= n) return;
    float f[F];
#pragma unroll
    for (int k = 0; k < F; k++) f[k] = feat[(size_t)i * F + k];
    float o[16];
#pragma unroll
    for (int d = 0; d < 16; d++) {
        float s = bs[d];
#pragma unroll
        for (int k = 0; k < F; k++) s += f[k] * Ws[k * 16 + d];
        o[d] = s;
    }
    float4* dst4 = (float4*)(out + (size_t)i * 16);
    dst4[0] = make_float4(o[0], o[1], o[2], o[3]);
    dst4[1] = make_float4(o[4], o[5], o[6], o[7]);
    dst4[2] = make_float4(o[8], o[9], o[10], o[11]);
    dst4[3] = make_float4(o[12], o[13], o[14], o[15]);
}

// ---------------------------------------------------------------------------
// Merged per-layer gather (round-4 version, plain loads): pre + nxt + sage +
// self in one kernel; 4 lanes per node, lane c owns float4 chunk c; in-deg
// normalizers from row lengths; FINAL fuses dot-product readout.
// ---------------------------------------------------------------------------
__device__ __forceinline__ void mm_accum(const float* __restrict__ Ws, float4 a, int c, float o[4]) {
#pragma unroll
    for (int g = 0; g < 4; ++g) {
        float a0 = __shfl(a.x, g, 4);
        float a1 = __shfl(a.y, g, 4);
        float a2 = __shfl(a.z, g, 4);
        float a3 = __shfl(a.w, g, 4);
        const float* wr = &Ws[(4 * g) * 16 + c * 4];
#pragma unroll
        for (int j = 0; j < 4; ++j)
            o[j] += a0 * wr[j] + a1 * wr[16 + j] + a2 * wr[32 + j] + a3 * wr[48 + j];
    }
}

template <bool FINAL>
__global__ void gather_layer(const float* __restrict__ cur, const float* __restrict__ hwk,
                             const int* __restrict__ adj_jj, const int2* __restrict__ adj_proc,
                             const int* __restrict__ off,
                             const float* __restrict__ sc_pre, const float* __restrict__ sc_nxt,
                             const float* __restrict__ Wp, const float* __restrict__ Wn,
                             const float* __restrict__ Wng, const float* __restrict__ Wsf,
                             const float* __restrict__ bp, const float* __restrict__ bn,
                             const float* __restrict__ bsg,
                             float* __restrict__ out, float* __restrict__ scores) {
    __shared__ float WpS[256], WnS[256], WngS[256], WsfS[256], bs[16];
    int t = threadIdx.x;
    WpS[t] = Wp[t]; WnS[t] = Wn[t]; WngS[t] = Wng[t]; WsfS[t] = Wsf[t];
    if (t < 16) bs[t] = bp[t] + bn[t] + bsg[t];
    __syncthreads();
    unsigned gid = blockIdx.x * 256 + t;
    unsigned v = gid >> 2, c = gid & 3;
    if (v >= N_JOB) return;
    const int* rend0 = off;
    const int* rend1 = off + N_JOB;
    const int* rend2 = off + 2 * N_JOB;
    int e0 = rend0[v], s0 = v ? rend0[v - 1] : 0;
    int e1 = rend1[v], s1 = v ? rend1[v - 1] : BASE_NXT;
    int e2 = rend2[v] - BASE_PROC;
    int s2 = (v ? rend2[v - 1] : BASE_PROC) - BASE_PROC;

    float4 accP = make_float4(0.f, 0.f, 0.f, 0.f);
    {
        int p = s0;
        for (; p + 1 < e0; p += 2) {
            int sa = adj_jj[p], sb = adj_jj[p + 1];
            float wa = sc_pre[sa], wb = sc_pre[sb];
            float4 ha = ((const float4*)(cur + (size_t)sa * 16))[c];
            float4 hb = ((const float4*)(cur + (size_t)sb * 16))[c];
            accP.x += ha.x * wa + hb.x * wb; accP.y += ha.y * wa + hb.y * wb;
            accP.z += ha.z * wa + hb.z * wb; accP.w += ha.w * wa + hb.w * wb;
        }
        if (p < e0) {
            int sa = adj_jj[p];
            float wa = sc_pre[sa];
            float4 ha = ((const float4*)(cur + (size_t)sa * 16))[c];
            accP.x += ha.x * wa; accP.y += ha.y * wa; accP.z += ha.z * wa; accP.w += ha.w * wa;
        }
    }
    float4 accN = make_float4(0.f, 0.f, 0.f, 0.f);
    {
        int p = s1;
        for (; p + 1 < e1; p += 2) {
            int sa = adj_jj[p], sb = adj_jj[p + 1];
            float wa = sc_nxt[sa], wb = sc_nxt[sb];
            float4 ha = ((const float4*)(cur + (size_t)sa * 16))[c];
            float4 hb = ((const float4*)(cur + (size_t)sb * 16))[c];
            accN.x += ha.x * wa + hb.x * wb; accN.y += ha.y * wa + hb.y * wb;
            accN.z += ha.z * wa + hb.z * wb; accN.w += ha.w * wa + hb.w * wb;
        }
        if (p < e1) {
            int sa = adj_jj[p];
            float wa = sc_nxt[sa];
            float4 ha = ((const float4*)(cur + (size_t)sa * 16))[c];
            accN.x += ha.x * wa; accN.y += ha.y * wa; accN.z += ha.z * wa; accN.w += ha.w * wa;
        }
    }
    float4 accS = make_float4(0.f, 0.f, 0.f, 0.f);
    {
        for (int p = s2; p < e2; ++p) {
            int sa = adj_proc[p].x;
            float4 ha = ((const float4*)(hwk + (size_t)sa * 16))[c];
            accS.x += ha.x; accS.y += ha.y; accS.z += ha.z; accS.w += ha.w;
        }
    }

    int d0 = e0 - s0, d1 = e1 - s1, d2 = e2 - s2;
    float rp = rsqrtf((float)(d0 < 1 ? 1 : d0));
    float rn = rsqrtf((float)(d1 < 1 ? 1 : d1));
    float ri = 1.0f / (float)(d2 < 1 ? 1 : d2);
    accP.x *= rp; accP.y *= rp; accP.z *= rp; accP.w *= rp;
    accN.x *= rn; accN.y *= rn; accN.z *= rn; accN.w *= rn;
    accS.x *= ri; accS.y *= ri; accS.z *= ri; accS.w *= ri;

    float o[4];
#pragma unroll
    for (int j = 0; j < 4; ++j) o[j] = bs[c * 4 + j];
    mm_accum(WpS, accP, c, o);
    mm_accum(WnS, accN, c, o);
    mm_accum(WngS, accS, c, o);
    float4 hself = ((const float4*)(cur + (size_t)v * 16))[c];
    mm_accum(WsfS, hself, c, o);
    ((float4*)(out + (size_t)v * 16))[c] = make_float4(o[0], o[1], o[2], o[3]);

    if (FINAL) {
        for (int p = s2; p < e2; ++p) {
            int2 pr = adj_proc[p];
            float4 wv = ((const float4*)(hwk + (size_t)pr.x * 16))[c];
            float d = o[0] * wv.x + o[1] * wv.y + o[2] * wv.z + o[3] * wv.w;
            d += __shfl_xor(d, 1, 4);
            d += __shfl_xor(d, 2, 4);
            if (c == 0) scores[pr.y] = d;
        }
    }
}

extern "C" void kernel_launch(void* const* d_in, const int* in_sizes, int n_in,
                              void* d_out, int out_size, void* d_ws, size_t ws_size,
                              hipStream_t stream) {
    const float* job_feat     = (const float*)d_in[0];
    const float* worker_feat  = (const float*)d_in[1];
    const int*   pre_src      = (const int*)d_in[2];
    const int*   pre_dst      = (const int*)d_in[3];
    const int*   nxt_src      = (const int*)d_in[4];
    const int*   nxt_dst      = (const int*)d_in[5];
    const int*   proc_src     = (const int*)d_in[6];
    const int*   proc_dst     = (const int*)d_in[7];
    const float* W_emb_job    = (const float*)d_in[8];
    const float* b_emb_job    = (const float*)d_in[9];
    const float* W_emb_worker = (const float*)d_in[10];
    const float* b_emb_worker = (const float*)d_in[11];
    const float* W_pre        = (const float*)d_in[12];
    const float* b_pre        = (const float*)d_in[13];
    const float* W_nxt        = (const float*)d_in[14];
    const float* b_nxt        = (const float*)d_in[15];
    const float* W_self       = (const float*)d_in[16];
    const float* W_neigh      = (const float*)d_in[17];
    const float* b_sage       = (const float*)d_in[18];
    float* out = (float*)d_out;

    // Workspace (~131 MB). Buckets alias hjA/hjB (dead before embed writes them).
    float* ws   = (float*)d_ws;
    unsigned* jjb = (unsigned*)ws;                       // 8,704,000 u32 (aliases hjA..)
    int2*  procb  = (int2*)(ws + 8704000);               // 2,176,000 int2 (ends at 13.056M < 16M)
    float* hjA  = ws;                                    // 8,000,000 f
    float* hjB  = hjA + (size_t)N_JOB * 16;              // 8,000,000 f
    float* hw   = hjB + (size_t)N_JOB * 16;              //   800,000 f
    float* rs   = hw + (size_t)N_WORKER * 16;            // 2,500,000 (deg ints -> norm floats)
    int*   off  = (int*)(rs + 5 * (size_t)N_JOB);        // 1,500,000
    int*   bsum = off + SCAN_N;                          // 1024
    int*   gcur = bsum + 1024;                           // 192 (+pad to 256)
    int*   adj_jj = gcur + 256;                          // 8,000,000
    int2*  adj_proc = (int2*)(adj_jj + (size_t)(E_PRE + E_NXT)); // 2,000,000 int2

    float* sc_pre = rs + 3 * (size_t)N_JOB;
    float* sc_nxt = rs + 4 * (size_t)N_JOB;

    hipMemsetAsync(rs, 0, (size_t)5 * N_JOB * sizeof(float), stream);
    cursor_init<<<1, 256, 0, stream>>>(gcur);

    // Single-pass partition of all 10M edges into dst-window buckets.
    const int PGRID = (E_TOT + 2047) / 2048;
    partition_kernel<<<PGRID, 256, 0, stream>>>(
        pre_src, pre_dst, nxt_src, nxt_dst, proc_src, proc_dst, gcur, jjb, procb);

    // In-degree count from buckets (hot set ~96 KB per active window).
    bucket_pass<false><<<NWIN * BPW, 256, 0, stream>>>(
        jjb, procb, gcur, (int*)rs, nullptr, nullptr);

    // CSR row offsets.
    scan_blocksum<<<SCAN_NB, 256, 0, stream>>>((const int*)rs, bsum, SCAN_N);
    scan_bsum<<<1, 1024, 0, stream>>>(bsum, SCAN_NB);
    scan_final<<<SCAN_NB, 256, 0, stream>>>((const int*)rs, bsum, off, SCAN_N);

    // Out-degrees: 4 x 1MB-hot windowed histogram passes.
    const int OGRID = (E_PRE + 1023) / 1024;
    for (int w = 0; w < 4; ++w) {
        int wlo = w * (N_JOB / 4);
        int whi = (w == 3) ? N_JOB : wlo + (N_JOB / 4);
        outdeg_win<<<OGRID, 256, 0, stream>>>(pre_src, nxt_src, (int*)rs, wlo, whi);
    }
    convert_out<<<(2 * N_JOB + 255) / 256, 256, 0, stream>>>(rs + 3 * (size_t)N_JOB);

    // Placement from buckets (off -> row ends; adj regions L2-hot per window).
    bucket_pass<true><<<NWIN * BPW, 256, 0, stream>>>(
        jjb, procb, gcur, off, adj_jj, adj_proc);

    embed_kernel<7><<<(N_JOB + 255) / 256, 256, 0, stream>>>(job_feat, W_emb_job, b_emb_job, hjA, N_JOB);
    embed_kernel<3><<<(N_WORKER + 255) / 256, 256, 0, stream>>>(worker_feat, W_emb_worker, b_emb_worker, hw, N_WORKER);

    const int GGRID = (4 * N_JOB + 255) / 256;
    gather_layer<false><<<GGRID, 256, 0, stream>>>(
        hjA, hw, adj_jj, adj_proc, off, sc_pre, sc_nxt,
        W_pre, W_nxt, W_neigh, W_self, b_pre, b_nxt, b_sage, hjB, nullptr);
    gather_layer<true><<<GGRID, 256, 0, stream>>>(
        hjB, hw, adj_jj, adj_proc, off, sc_pre, sc_nxt,
        W_pre, W_nxt, W_neigh, W_self, b_pre, b_nxt, b_sage, hjA, out);
}

// Round 7
// 905.835 us; speedup vs baseline: 2.0908x; 1.9926x over previous
//
#include <hip/hip_runtime.h>

#define N_JOB 500000
#define N_WORKER 50000
#define E_PRE 4000000
#define E_NXT 4000000
#define E_PROC 2000000

// dst/src-window partition: 62 windows x 8192 nodes
#define WBITS 13
#define WSZ 8192
#define NWIN 62                    // ceil(500000/8192)
#define CAP_JJ 67584               // mean 65536 + 8 sigma (sigma ~254)
#define CAP_PR 34000               // mean 32768 + 6.8 sigma
#define CAP_SR 67584

#define EPB 8192                   // edges per partition block
#define NB_PRE ((E_PRE + EPB - 1) / EPB)     // 489
#define NB_PROC ((E_PROC + EPB - 1) / EPB)   // 245

// gcur layout: [0,62) rel0-dst | [62,124) rel1-dst | [124,186) proc-dst
//              [186,248) rel0-src | [248,310) rel1-src
__global__ void cursor_init(int* __restrict__ gcur) {
    int t = threadIdx.x;
    if (t < 2 * NWIN) gcur[t] = t * CAP_JJ;
    else if (t < 3 * NWIN) gcur[t] = (t - 2 * NWIN) * CAP_PR;
    else if (t < 5 * NWIN) gcur[t] = (t - 3 * NWIN) * CAP_SR;
}

// ---------------------------------------------------------------------------
// Partition: each block owns 8192 edges of one relation. LDS histogram by
// window -> one global cursor reservation per (block,segment) (~136K atomics
// total) -> replay (re-read, L2-hot) writing packed bucket entries with plain
// stores in ~130-entry runs. jj entry: (dst&8191)<<19|src. proc: ((dl<<16)|src, eid).
// src entry: u16 src&8191.
// ---------------------------------------------------------------------------
__global__ __launch_bounds__(256) void partition_kernel(
        const int* __restrict__ pre_src, const int* __restrict__ pre_dst,
        const int* __restrict__ nxt_src, const int* __restrict__ nxt_dst,
        const int* __restrict__ proc_src, const int* __restrict__ proc_dst,
        int* __restrict__ gcur, unsigned* __restrict__ jjb,
        int2* __restrict__ procb, unsigned short* __restrict__ srcb) {
    __shared__ int cntD[NWIN], cntS[NWIN], basD[NWIN], basS[NWIN];
    __shared__ int curD[NWIN], curS[NWIN];
    int t = threadIdx.x;
    int b = blockIdx.x;
    int rel, lo, hi;
    const int *dstp, *srcp;
    if (b < NB_PRE) {
        rel = 0; dstp = pre_dst; srcp = pre_src;
        lo = b * EPB; hi = min(lo + EPB, E_PRE);
    } else if (b < 2 * NB_PRE) {
        rel = 1; b -= NB_PRE; dstp = nxt_dst; srcp = nxt_src;
        lo = b * EPB; hi = min(lo + EPB, E_NXT);
    } else {
        rel = 2; b -= 2 * NB_PRE; dstp = proc_dst; srcp = proc_src;
        lo = b * EPB; hi = min(lo + EPB, E_PROC);
    }
    if (t < NWIN) { cntD[t] = 0; cntS[t] = 0; }
    __syncthreads();
    if (rel < 2) {
        for (int i = lo + t; i < hi; i += 256) {
            atomicAdd(&cntD[dstp[i] >> WBITS], 1);
            atomicAdd(&cntS[srcp[i] >> WBITS], 1);
        }
        __syncthreads();
        if (t < NWIN) {
            int c = cntD[t];
            basD[t] = c ? atomicAdd(&gcur[rel * NWIN + t], c) : 0;
            c = cntS[t];
            basS[t] = c ? atomicAdd(&gcur[3 * NWIN + rel * NWIN + t], c) : 0;
            curD[t] = 0; curS[t] = 0;
        }
        __syncthreads();
        for (int i = lo + t; i < hi; i += 256) {
            int d = dstp[i], s = srcp[i];
            int wd = d >> WBITS, wsw = s >> WBITS;
            int pD = basD[wd] + atomicAdd(&curD[wd], 1);
            jjb[pD] = ((unsigned)(d & (WSZ - 1)) << 19) | (unsigned)s;
            int pS = basS[wsw] + atomicAdd(&curS[wsw], 1);
            srcb[pS] = (unsigned short)(s & (WSZ - 1));
        }
    } else {
        for (int i = lo + t; i < hi; i += 256)
            atomicAdd(&cntD[dstp[i] >> WBITS], 1);
        __syncthreads();
        if (t < NWIN) {
            int c = cntD[t];
            basD[t] = c ? atomicAdd(&gcur[2 * NWIN + t], c) : 0;
            curD[t] = 0;
        }
        __syncthreads();
        for (int i = lo + t; i < hi; i += 256) {
            int d = dstp[i], s = srcp[i];
            int wd = d >> WBITS;
            int pD = basD[wd] + atomicAdd(&curD[wd], 1);
            procb[pD] = make_int2(((d & (WSZ - 1)) << 16) | s, i);
        }
    }
}

// ---------------------------------------------------------------------------
// csr_build: one block per (rel,window). Fuses count + scan + place with LDS
// only: histogram segment -> block scan -> write row ENDS to off -> scatter
// into own contiguous adj region via LDS cursors (plain stores, L2-merged).
// ---------------------------------------------------------------------------
__global__ __launch_bounds__(256) void csr_build(
        const unsigned* __restrict__ jjb, const int2* __restrict__ procb,
        const int* __restrict__ gcur, int* __restrict__ off,
        int* __restrict__ adj_jj, int2* __restrict__ adj_proc) {
    __shared__ int hist[WSZ];
    __shared__ int scanB[WSZ];
    __shared__ int part[256];
    __shared__ int wcnt[NWIN];
    __shared__ int baseS;
    int t = threadIdx.x;
    int rel = blockIdx.x / NWIN;
    int w = blockIdx.x % NWIN;
    int segbase, segend;
    if (rel < 2) { int k = rel * NWIN + w; segbase = k * CAP_JJ; segend = gcur[k]; }
    else         { segbase = w * CAP_PR; segend = gcur[2 * NWIN + w]; }
    if (t < NWIN) {
        if (rel < 2) wcnt[t] = gcur[rel * NWIN + t] - (rel * NWIN + t) * CAP_JJ;
        else         wcnt[t] = gcur[2 * NWIN + t] - t * CAP_PR;
    }
    for (int i = t; i < WSZ; i += 256) hist[i] = 0;
    __syncthreads();
    if (t == 0) {
        int bb = (rel == 1) ? E_PRE : 0;
        for (int i = 0; i < w; ++i) bb += wcnt[i];
        baseS = bb;
    }
    if (rel < 2) {
        for (int p = segbase + t; p < segend; p += 256)
            atomicAdd(&hist[jjb[p] >> 19], 1);
    } else {
        for (int p = segbase + t; p < segend; p += 256)
            atomicAdd(&hist[procb[p].x >> 16], 1);
    }
    __syncthreads();
    // exclusive block scan of hist -> scanB (+ csr base)
    {
        int mb = t * 32;
        int sum = 0;
        for (int j = 0; j < 32; ++j) { int v = hist[mb + j]; scanB[mb + j] = sum; sum += v; }
        part[t] = sum;
        __syncthreads();
        if (t == 0) { int r = 0; for (int i = 0; i < 256; ++i) { int v = part[i]; part[i] = r; r += v; } }
        __syncthreads();
        int add = part[t] + baseS;
        for (int j = 0; j < 32; ++j) scanB[mb + j] += add;
    }
    __syncthreads();
    int nlo = w * WSZ;
    int nloc = min(WSZ, N_JOB - nlo);
    for (int i = t; i < nloc; i += 256)
        off[rel * N_JOB + nlo + i] = scanB[i] + hist[i];   // row ENDS
    __syncthreads();
    // scatter via LDS cursors
    if (rel < 2) {
        for (int p = segbase + t; p < segend; p += 256) {
            unsigned e = jjb[p];
            int slot = atomicAdd(&scanB[e >> 19], 1);
            adj_jj[slot] = (int)(e & 0x7FFFFu);
        }
    } else {
        for (int p = segbase + t; p < segend; p += 256) {
            int2 e = procb[p];
            int slot = atomicAdd(&scanB[e.x >> 16], 1);
            adj_proc[slot] = make_int2(e.x & 0xFFFF, e.y);
        }
    }
}

// ---------------------------------------------------------------------------
// outdeg_build: one block per (rel,window); LDS histogram of u16 src-locals,
// writes rsqrt(max(deg,1)) floats directly (no global deg array, no atomics).
// ---------------------------------------------------------------------------
__global__ __launch_bounds__(256) void outdeg_build(
        const unsigned short* __restrict__ srcb, const int* __restrict__ gcur,
        float* __restrict__ sc_pre, float* __restrict__ sc_nxt) {
    __shared__ int hist[WSZ];
    int t = threadIdx.x;
    int rel = blockIdx.x / NWIN;
    int w = blockIdx.x % NWIN;
    int k = rel * NWIN + w;
    int segbase = k * CAP_SR;
    int segend = gcur[3 * NWIN + k];
    for (int i = t; i < WSZ; i += 256) hist[i] = 0;
    __syncthreads();
    int cnt = segend - segbase;
    const unsigned* p2 = (const unsigned*)(srcb + segbase);
    int n2 = cnt >> 1;
    for (int i = t; i < n2; i += 256) {
        unsigned v = p2[i];
        atomicAdd(&hist[v & 0xFFFFu], 1);
        atomicAdd(&hist[v >> 16], 1);
    }
    if (t == 0 && (cnt & 1)) atomicAdd(&hist[srcb[segend - 1]], 1);
    __syncthreads();
    float* scp = rel ? sc_nxt : sc_pre;
    int nlo = w * WSZ;
    int nloc = min(WSZ, N_JOB - nlo);
    for (int i = t; i < nloc; i += 256) {
        int d = hist[i];
        scp[nlo + i] = rsqrtf((float)(d < 1 ? 1 : d));
    }
}

// ---------------------------------------------------------------------------
// Embedding: one thread per row, weights staged in LDS.
// ---------------------------------------------------------------------------
template <int F>
__global__ void embed_kernel(const float* __restrict__ feat, const float* __restrict__ W,
                             const float* __restrict__ b, float* __restrict__ out, int n) {
    __shared__ float Ws[F * 16];
    __shared__ float bs[16];
    int t = threadIdx.x;
    if (t < F * 16) Ws[t] = W[t];
    if (t < 16) bs[t] = b[t];
    __syncthreads();
    int i = blockIdx.x * blockDim.x + t;
    if (i >= n) return;
    float f[F];
#pragma unroll
    for (int k = 0; k < F; k++) f[k] = feat[(size_t)i * F + k];
    float o[16];
#pragma unroll
    for (int d = 0; d < 16; d++) {
        float s = bs[d];
#pragma unroll
        for (int k = 0; k < F; k++) s += f[k] * Ws[k * 16 + d];
        o[d] = s;
    }
    float4* dst4 = (float4*)(out + (size_t)i * 16);
    dst4[0] = make_float4(o[0], o[1], o[2], o[3]);
    dst4[1] = make_float4(o[4], o[5], o[6], o[7]);
    dst4[2] = make_float4(o[8], o[9], o[10], o[11]);
    dst4[3] = make_float4(o[12], o[13], o[14], o[15]);
}

// ---------------------------------------------------------------------------
// Merged per-layer gather: pre + nxt + sage + self; 4 lanes per node, lane c
// owns float4 chunk c; in-deg normalizers from row lengths; FINAL fuses the
// dot-product readout. adj_proc rows are 0-based into adj_proc.
// ---------------------------------------------------------------------------
__device__ __forceinline__ void mm_accum(const float* __restrict__ Ws, float4 a, int c, float o[4]) {
#pragma unroll
    for (int g = 0; g < 4; ++g) {
        float a0 = __shfl(a.x, g, 4);
        float a1 = __shfl(a.y, g, 4);
        float a2 = __shfl(a.z, g, 4);
        float a3 = __shfl(a.w, g, 4);
        const float* wr = &Ws[(4 * g) * 16 + c * 4];
#pragma unroll
        for (int j = 0; j < 4; ++j)
            o[j] += a0 * wr[j] + a1 * wr[16 + j] + a2 * wr[32 + j] + a3 * wr[48 + j];
    }
}

template <bool FINAL>
__global__ void gather_layer(const float* __restrict__ cur, const float* __restrict__ hwk,
                             const int* __restrict__ adj_jj, const int2* __restrict__ adj_proc,
                             const int* __restrict__ off,
                             const float* __restrict__ sc_pre, const float* __restrict__ sc_nxt,
                             const float* __restrict__ Wp, const float* __restrict__ Wn,
                             const float* __restrict__ Wng, const float* __restrict__ Wsf,
                             const float* __restrict__ bp, const float* __restrict__ bn,
                             const float* __restrict__ bsg,
                             float* __restrict__ out, float* __restrict__ scores) {
    __shared__ float WpS[256], WnS[256], WngS[256], WsfS[256], bs[16];
    int t = threadIdx.x;
    WpS[t] = Wp[t]; WnS[t] = Wn[t]; WngS[t] = Wng[t]; WsfS[t] = Wsf[t];
    if (t < 16) bs[t] = bp[t] + bn[t] + bsg[t];
    __syncthreads();
    unsigned gid = blockIdx.x * 256 + t;
    unsigned v = gid >> 2, c = gid & 3;
    if (v >= N_JOB) return;
    const int* rend0 = off;
    const int* rend1 = off + N_JOB;
    const int* rend2 = off + 2 * N_JOB;
    int e0 = rend0[v], s0 = v ? rend0[v - 1] : 0;
    int e1 = rend1[v], s1 = v ? rend1[v - 1] : E_PRE;
    int e2 = rend2[v], s2 = v ? rend2[v - 1] : 0;

    float4 accP = make_float4(0.f, 0.f, 0.f, 0.f);
    {
        int p = s0;
        for (; p + 1 < e0; p += 2) {
            int sa = adj_jj[p], sb = adj_jj[p + 1];
            float wa = sc_pre[sa], wb = sc_pre[sb];
            float4 ha = ((const float4*)(cur + (size_t)sa * 16))[c];
            float4 hb = ((const float4*)(cur + (size_t)sb * 16))[c];
            accP.x += ha.x * wa + hb.x * wb; accP.y += ha.y * wa + hb.y * wb;
            accP.z += ha.z * wa + hb.z * wb; accP.w += ha.w * wa + hb.w * wb;
        }
        if (p < e0) {
            int sa = adj_jj[p];
            float wa = sc_pre[sa];
            float4 ha = ((const float4*)(cur + (size_t)sa * 16))[c];
            accP.x += ha.x * wa; accP.y += ha.y * wa; accP.z += ha.z * wa; accP.w += ha.w * wa;
        }
    }
    float4 accN = make_float4(0.f, 0.f, 0.f, 0.f);
    {
        int p = s1;
        for (; p + 1 < e1; p += 2) {
            int sa = adj_jj[p], sb = adj_jj[p + 1];
            float wa = sc_nxt[sa], wb = sc_nxt[sb];
            float4 ha = ((const float4*)(cur + (size_t)sa * 16))[c];
            float4 hb = ((const float4*)(cur + (size_t)sb * 16))[c];
            accN.x += ha.x * wa + hb.x * wb; accN.y += ha.y * wa + hb.y * wb;
            accN.z += ha.z * wa + hb.z * wb; accN.w += ha.w * wa + hb.w * wb;
        }
        if (p < e1) {
            int sa = adj_jj[p];
            float wa = sc_nxt[sa];
            float4 ha = ((const float4*)(cur + (size_t)sa * 16))[c];
            accN.x += ha.x * wa; accN.y += ha.y * wa; accN.z += ha.z * wa; accN.w += ha.w * wa;
        }
    }
    float4 accS = make_float4(0.f, 0.f, 0.f, 0.f);
    for (int p = s2; p < e2; ++p) {
        int sa = adj_proc[p].x;
        float4 ha = ((const float4*)(hwk + (size_t)sa * 16))[c];
        accS.x += ha.x; accS.y += ha.y; accS.z += ha.z; accS.w += ha.w;
    }

    int d0 = e0 - s0, d1 = e1 - s1, d2 = e2 - s2;
    float rp = rsqrtf((float)(d0 < 1 ? 1 : d0));
    float rn = rsqrtf((float)(d1 < 1 ? 1 : d1));
    float ri = 1.0f / (float)(d2 < 1 ? 1 : d2);
    accP.x *= rp; accP.y *= rp; accP.z *= rp; accP.w *= rp;
    accN.x *= rn; accN.y *= rn; accN.z *= rn; accN.w *= rn;
    accS.x *= ri; accS.y *= ri; accS.z *= ri; accS.w *= ri;

    float o[4];
#pragma unroll
    for (int j = 0; j < 4; ++j) o[j] = bs[c * 4 + j];
    mm_accum(WpS, accP, c, o);
    mm_accum(WnS, accN, c, o);
    mm_accum(WngS, accS, c, o);
    float4 hself = ((const float4*)(cur + (size_t)v * 16))[c];
    mm_accum(WsfS, hself, c, o);
    ((float4*)(out + (size_t)v * 16))[c] = make_float4(o[0], o[1], o[2], o[3]);

    if (FINAL) {
        for (int p = s2; p < e2; ++p) {
            int2 pr = adj_proc[p];
            float4 wv = ((const float4*)(hwk + (size_t)pr.x * 16))[c];
            float d = o[0] * wv.x + o[1] * wv.y + o[2] * wv.z + o[3] * wv.w;
            d += __shfl_xor(d, 1, 4);
            d += __shfl_xor(d, 2, 4);
            if (c == 0) scores[pr.y] = d;
        }
    }
}

extern "C" void kernel_launch(void* const* d_in, const int* in_sizes, int n_in,
                              void* d_out, int out_size, void* d_ws, size_t ws_size,
                              hipStream_t stream) {
    const float* job_feat     = (const float*)d_in[0];
    const float* worker_feat  = (const float*)d_in[1];
    const int*   pre_src      = (const int*)d_in[2];
    const int*   pre_dst      = (const int*)d_in[3];
    const int*   nxt_src      = (const int*)d_in[4];
    const int*   nxt_dst      = (const int*)d_in[5];
    const int*   proc_src     = (const int*)d_in[6];
    const int*   proc_dst     = (const int*)d_in[7];
    const float* W_emb_job    = (const float*)d_in[8];
    const float* b_emb_job    = (const float*)d_in[9];
    const float* W_emb_worker = (const float*)d_in[10];
    const float* b_emb_worker = (const float*)d_in[11];
    const float* W_pre        = (const float*)d_in[12];
    const float* b_pre        = (const float*)d_in[13];
    const float* W_nxt        = (const float*)d_in[14];
    const float* b_nxt        = (const float*)d_in[15];
    const float* W_self       = (const float*)d_in[16];
    const float* W_neigh      = (const float*)d_in[17];
    const float* b_sage       = (const float*)d_in[18];
    float* out = (float*)d_out;

    // Workspace (~125 MB). Buckets alias hjA/hjB/hw (dead until embed).
    float* ws = (float*)d_ws;
    float* hjA = ws;                                    // 8,000,000 f
    float* hjB = ws + 8000000;                          // 8,000,000 f
    float* hw  = ws + 16000000;                         //   800,000 f
    unsigned* jjb = (unsigned*)ws;                      // 124*67584 = 8,380,416 u32
    int2*  procb  = (int2*)(ws + 8380416);              // 62*34000 int2 = 4,216,000 u32
    unsigned short* srcb = (unsigned short*)(ws + 12596416); // 124*67584 u16 = 4,190,208 u32
    int*   off  = (int*)(ws + 16800000);                // 1,500,000 (row ends)
    int*   gcur = off + 3 * N_JOB;                      // 512
    int*   adj_jj = gcur + 512;                         // 8,000,000
    int2*  adj_proc = (int2*)(adj_jj + 8000000);        // 2,000,000 int2
    float* sc_pre = (float*)(adj_proc + 2000000);       // 500,000
    float* sc_nxt = sc_pre + N_JOB;                     // 500,000

    cursor_init<<<1, 512, 0, stream>>>(gcur);
    partition_kernel<<<2 * NB_PRE + NB_PROC, 256, 0, stream>>>(
        pre_src, pre_dst, nxt_src, nxt_dst, proc_src, proc_dst,
        gcur, jjb, procb, srcb);
    csr_build<<<3 * NWIN, 256, 0, stream>>>(jjb, procb, gcur, off, adj_jj, adj_proc);
    outdeg_build<<<2 * NWIN, 256, 0, stream>>>(srcb, gcur, sc_pre, sc_nxt);

    embed_kernel<7><<<(N_JOB + 255) / 256, 256, 0, stream>>>(job_feat, W_emb_job, b_emb_job, hjA, N_JOB);
    embed_kernel<3><<<(N_WORKER + 255) / 256, 256, 0, stream>>>(worker_feat, W_emb_worker, b_emb_worker, hw, N_WORKER);

    const int GGRID = (4 * N_JOB + 255) / 256;
    gather_layer<false><<<GGRID, 256, 0, stream>>>(
        hjA, hw, adj_jj, adj_proc, off, sc_pre, sc_nxt,
        W_pre, W_nxt, W_neigh, W_self, b_pre, b_nxt, b_sage, hjB, nullptr);
    gather_layer<true><<<GGRID, 256, 0, stream>>>(
        hjB, hw, adj_jj, adj_proc, off, sc_pre, sc_nxt,
        W_pre, W_nxt, W_neigh, W_self, b_pre, b_nxt, b_sage, hjA, out);
}

// Round 8
// 870.079 us; speedup vs baseline: 2.1767x; 1.0411x over previous
//
#include <hip/hip_runtime.h>
#include <hip/hip_fp16.h>

#define N_JOB 500000
#define N_WORKER 50000
#define E_PRE 4000000
#define E_NXT 4000000
#define E_PROC 2000000

// dst/src-window partition: 62 windows x 8192 nodes
#define WBITS 13
#define WSZ 8192
#define NWIN 62                    // ceil(500000/8192)
#define CAP_JJ 67584               // mean 65536 + 8 sigma (sigma ~254)
#define CAP_PR 34000               // mean 32768 + 6.8 sigma
#define CAP_SR 67584

#define EPB 8192                   // edges per partition block
#define NB_PRE ((E_PRE + EPB - 1) / EPB)     // 489
#define NB_PROC ((E_PROC + EPB - 1) / EPB)   // 245

// gcur layout: [0,62) rel0-dst | [62,124) rel1-dst | [124,186) proc-dst
//              [186,248) rel0-src | [248,310) rel1-src
__global__ void cursor_init(int* __restrict__ gcur) {
    int t = threadIdx.x;
    if (t < 2 * NWIN) gcur[t] = t * CAP_JJ;
    else if (t < 3 * NWIN) gcur[t] = (t - 2 * NWIN) * CAP_PR;
    else if (t < 5 * NWIN) gcur[t] = (t - 3 * NWIN) * CAP_SR;
}

// ---------------------------------------------------------------------------
// Partition: each block owns 8192 edges of one relation. LDS histogram by
// window -> one global cursor reservation per (block,segment) -> replay
// writing packed bucket entries with plain stores.
// jj entry: (dst&8191)<<19|src. proc: ((dl<<16)|src, eid). src entry: u16.
// ---------------------------------------------------------------------------
__global__ __launch_bounds__(256) void partition_kernel(
        const int* __restrict__ pre_src, const int* __restrict__ pre_dst,
        const int* __restrict__ nxt_src, const int* __restrict__ nxt_dst,
        const int* __restrict__ proc_src, const int* __restrict__ proc_dst,
        int* __restrict__ gcur, unsigned* __restrict__ jjb,
        int2* __restrict__ procb, unsigned short* __restrict__ srcb) {
    __shared__ int cntD[NWIN], cntS[NWIN], basD[NWIN], basS[NWIN];
    __shared__ int curD[NWIN], curS[NWIN];
    int t = threadIdx.x;
    int b = blockIdx.x;
    int rel, lo, hi;
    const int *dstp, *srcp;
    if (b < NB_PRE) {
        rel = 0; dstp = pre_dst; srcp = pre_src;
        lo = b * EPB; hi = min(lo + EPB, E_PRE);
    } else if (b < 2 * NB_PRE) {
        rel = 1; b -= NB_PRE; dstp = nxt_dst; srcp = nxt_src;
        lo = b * EPB; hi = min(lo + EPB, E_NXT);
    } else {
        rel = 2; b -= 2 * NB_PRE; dstp = proc_dst; srcp = proc_src;
        lo = b * EPB; hi = min(lo + EPB, E_PROC);
    }
    if (t < NWIN) { cntD[t] = 0; cntS[t] = 0; }
    __syncthreads();
    if (rel < 2) {
        for (int i = lo + t; i < hi; i += 256) {
            atomicAdd(&cntD[dstp[i] >> WBITS], 1);
            atomicAdd(&cntS[srcp[i] >> WBITS], 1);
        }
        __syncthreads();
        if (t < NWIN) {
            int c = cntD[t];
            basD[t] = c ? atomicAdd(&gcur[rel * NWIN + t], c) : 0;
            c = cntS[t];
            basS[t] = c ? atomicAdd(&gcur[3 * NWIN + rel * NWIN + t], c) : 0;
            curD[t] = 0; curS[t] = 0;
        }
        __syncthreads();
        for (int i = lo + t; i < hi; i += 256) {
            int d = dstp[i], s = srcp[i];
            int wd = d >> WBITS, wsw = s >> WBITS;
            int pD = basD[wd] + atomicAdd(&curD[wd], 1);
            jjb[pD] = ((unsigned)(d & (WSZ - 1)) << 19) | (unsigned)s;
            int pS = basS[wsw] + atomicAdd(&curS[wsw], 1);
            srcb[pS] = (unsigned short)(s & (WSZ - 1));
        }
    } else {
        for (int i = lo + t; i < hi; i += 256)
            atomicAdd(&cntD[dstp[i] >> WBITS], 1);
        __syncthreads();
        if (t < NWIN) {
            int c = cntD[t];
            basD[t] = c ? atomicAdd(&gcur[2 * NWIN + t], c) : 0;
            curD[t] = 0;
        }
        __syncthreads();
        for (int i = lo + t; i < hi; i += 256) {
            int d = dstp[i], s = srcp[i];
            int wd = d >> WBITS;
            int pD = basD[wd] + atomicAdd(&curD[wd], 1);
            procb[pD] = make_int2(((d & (WSZ - 1)) << 16) | s, i);
        }
    }
}

// ---------------------------------------------------------------------------
// csr_build: one block per (rel,window). Fuses count + scan + place with LDS
// only; writes row ENDS + scatters into own contiguous adj region.
// ---------------------------------------------------------------------------
__global__ __launch_bounds__(256) void csr_build(
        const unsigned* __restrict__ jjb, const int2* __restrict__ procb,
        const int* __restrict__ gcur, int* __restrict__ off,
        int* __restrict__ adj_jj, int2* __restrict__ adj_proc) {
    __shared__ int hist[WSZ];
    __shared__ int scanB[WSZ];
    __shared__ int part[256];
    __shared__ int wcnt[NWIN];
    __shared__ int baseS;
    int t = threadIdx.x;
    int rel = blockIdx.x / NWIN;
    int w = blockIdx.x % NWIN;
    int segbase, segend;
    if (rel < 2) { int k = rel * NWIN + w; segbase = k * CAP_JJ; segend = gcur[k]; }
    else         { segbase = w * CAP_PR; segend = gcur[2 * NWIN + w]; }
    if (t < NWIN) {
        if (rel < 2) wcnt[t] = gcur[rel * NWIN + t] - (rel * NWIN + t) * CAP_JJ;
        else         wcnt[t] = gcur[2 * NWIN + t] - t * CAP_PR;
    }
    for (int i = t; i < WSZ; i += 256) hist[i] = 0;
    __syncthreads();
    if (t == 0) {
        int bb = (rel == 1) ? E_PRE : 0;
        for (int i = 0; i < w; ++i) bb += wcnt[i];
        baseS = bb;
    }
    if (rel < 2) {
        for (int p = segbase + t; p < segend; p += 256)
            atomicAdd(&hist[jjb[p] >> 19], 1);
    } else {
        for (int p = segbase + t; p < segend; p += 256)
            atomicAdd(&hist[procb[p].x >> 16], 1);
    }
    __syncthreads();
    {
        int mb = t * 32;
        int sum = 0;
        for (int j = 0; j < 32; ++j) { int v = hist[mb + j]; scanB[mb + j] = sum; sum += v; }
        part[t] = sum;
        __syncthreads();
        if (t == 0) { int r = 0; for (int i = 0; i < 256; ++i) { int v = part[i]; part[i] = r; r += v; } }
        __syncthreads();
        int add = part[t] + baseS;
        for (int j = 0; j < 32; ++j) scanB[mb + j] += add;
    }
    __syncthreads();
    int nlo = w * WSZ;
    int nloc = min(WSZ, N_JOB - nlo);
    for (int i = t; i < nloc; i += 256)
        off[rel * N_JOB + nlo + i] = scanB[i] + hist[i];   // row ENDS
    __syncthreads();
    if (rel < 2) {
        for (int p = segbase + t; p < segend; p += 256) {
            unsigned e = jjb[p];
            int slot = atomicAdd(&scanB[e >> 19], 1);
            adj_jj[slot] = (int)(e & 0x7FFFFu);
        }
    } else {
        for (int p = segbase + t; p < segend; p += 256) {
            int2 e = procb[p];
            int slot = atomicAdd(&scanB[e.x >> 16], 1);
            adj_proc[slot] = make_int2(e.x & 0xFFFF, e.y);
        }
    }
}

// ---------------------------------------------------------------------------
// outdeg_build: one block per (rel,window); LDS histogram of u16 src-locals,
// writes rsqrt(max(deg,1)) floats directly.
// ---------------------------------------------------------------------------
__global__ __launch_bounds__(256) void outdeg_build(
        const unsigned short* __restrict__ srcb, const int* __restrict__ gcur,
        float* __restrict__ sc_pre, float* __restrict__ sc_nxt) {
    __shared__ int hist[WSZ];
    int t = threadIdx.x;
    int rel = blockIdx.x / NWIN;
    int w = blockIdx.x % NWIN;
    int k = rel * NWIN + w;
    int segbase = k * CAP_SR;
    int segend = gcur[3 * NWIN + k];
    for (int i = t; i < WSZ; i += 256) hist[i] = 0;
    __syncthreads();
    int cnt = segend - segbase;
    const unsigned* p2 = (const unsigned*)(srcb + segbase);
    int n2 = cnt >> 1;
    for (int i = t; i < n2; i += 256) {
        unsigned v = p2[i];
        atomicAdd(&hist[v & 0xFFFFu], 1);
        atomicAdd(&hist[v >> 16], 1);
    }
    if (t == 0 && (cnt & 1)) atomicAdd(&hist[srcb[segend - 1]], 1);
    __syncthreads();
    float* scp = rel ? sc_nxt : sc_pre;
    int nlo = w * WSZ;
    int nloc = min(WSZ, N_JOB - nlo);
    for (int i = t; i < nloc; i += 256) {
        int d = hist[i];
        scp[nlo + i] = rsqrtf((float)(d < 1 ? 1 : d));
    }
}

__device__ __forceinline__ unsigned pack_h2(float a, float b) {
    __half2 h = __float22half2_rn(make_float2(a, b));
    return *reinterpret_cast<unsigned*>(&h);
}
__device__ __forceinline__ float2 unpack_h2(unsigned u) {
    __half2 h = *reinterpret_cast<__half2*>(&u);
    return __half22float2(h);
}

// ---------------------------------------------------------------------------
// Embedding. HOUT=true: write fp16 row (16 halfs). HOUT=false: f32 row (hw).
// ---------------------------------------------------------------------------
template <int F, bool HOUT>
__global__ void embed_kernel(const float* __restrict__ feat, const float* __restrict__ W,
                             const float* __restrict__ b, void* __restrict__ outp, int n) {
    __shared__ float Ws[F * 16];
    __shared__ float bs[16];
    int t = threadIdx.x;
    if (t < F * 16) Ws[t] = W[t];
    if (t < 16) bs[t] = b[t];
    __syncthreads();
    int i = blockIdx.x * blockDim.x + t;
    if (i >= n) return;
    float f[F];
#pragma unroll
    for (int k = 0; k < F; k++) f[k] = feat[(size_t)i * F + k];
    float o[16];
#pragma unroll
    for (int d = 0; d < 16; d++) {
        float s = bs[d];
#pragma unroll
        for (int k = 0; k < F; k++) s += f[k] * Ws[k * 16 + d];
        o[d] = s;
    }
    if (HOUT) {
        uint4* dst = (uint4*)((__half*)outp + (size_t)i * 16);
        dst[0] = make_uint4(pack_h2(o[0], o[1]), pack_h2(o[2], o[3]),
                            pack_h2(o[4], o[5]), pack_h2(o[6], o[7]));
        dst[1] = make_uint4(pack_h2(o[8], o[9]), pack_h2(o[10], o[11]),
                            pack_h2(o[12], o[13]), pack_h2(o[14], o[15]));
    } else {
        float4* dst4 = (float4*)((float*)outp + (size_t)i * 16);
        dst4[0] = make_float4(o[0], o[1], o[2], o[3]);
        dst4[1] = make_float4(o[4], o[5], o[6], o[7]);
        dst4[2] = make_float4(o[8], o[9], o[10], o[11]);
        dst4[3] = make_float4(o[12], o[13], o[14], o[15]);
    }
}

// ---------------------------------------------------------------------------
// Merged per-layer gather with fp16 node features: pre + nxt + sage + self.
// 4 lanes per node; lane c owns elements [4c,4c+4). fp16 rows are 32 B, so
// the gathered array is 16 MB (2x line utilization, 2x L2 coverage vs f32).
// Accumulation/weights f32. FINAL writes scores only (no h output).
// ---------------------------------------------------------------------------
__device__ __forceinline__ void mm_accum(const float* __restrict__ Ws, float4 a, int c, float o[4]) {
#pragma unroll
    for (int g = 0; g < 4; ++g) {
        float a0 = __shfl(a.x, g, 4);
        float a1 = __shfl(a.y, g, 4);
        float a2 = __shfl(a.z, g, 4);
        float a3 = __shfl(a.w, g, 4);
        const float* wr = &Ws[(4 * g) * 16 + c * 4];
#pragma unroll
        for (int j = 0; j < 4; ++j)
            o[j] += a0 * wr[j] + a1 * wr[16 + j] + a2 * wr[32 + j] + a3 * wr[48 + j];
    }
}

__device__ __forceinline__ float4 load_h16(const __half* __restrict__ h16, int row, int c) {
    uint2 raw = *(const uint2*)(h16 + (size_t)row * 16 + c * 4);
    float2 lo = unpack_h2(raw.x), hi = unpack_h2(raw.y);
    return make_float4(lo.x, lo.y, hi.x, hi.y);
}

template <bool FINAL>
__global__ void gather_layer(const __half* __restrict__ cur, const float* __restrict__ hwk,
                             const int* __restrict__ adj_jj, const int2* __restrict__ adj_proc,
                             const int* __restrict__ off,
                             const float* __restrict__ sc_pre, const float* __restrict__ sc_nxt,
                             const float* __restrict__ Wp, const float* __restrict__ Wn,
                             const float* __restrict__ Wng, const float* __restrict__ Wsf,
                             const float* __restrict__ bp, const float* __restrict__ bn,
                             const float* __restrict__ bsg,
                             __half* __restrict__ out, float* __restrict__ scores) {
    __shared__ float WpS[256], WnS[256], WngS[256], WsfS[256], bs[16];
    int t = threadIdx.x;
    WpS[t] = Wp[t]; WnS[t] = Wn[t]; WngS[t] = Wng[t]; WsfS[t] = Wsf[t];
    if (t < 16) bs[t] = bp[t] + bn[t] + bsg[t];
    __syncthreads();
    unsigned gid = blockIdx.x * 256 + t;
    unsigned v = gid >> 2, c = gid & 3;
    if (v >= N_JOB) return;
    const int* rend0 = off;
    const int* rend1 = off + N_JOB;
    const int* rend2 = off + 2 * N_JOB;
    int e0 = rend0[v], s0 = v ? rend0[v - 1] : 0;
    int e1 = rend1[v], s1 = v ? rend1[v - 1] : E_PRE;
    int e2 = rend2[v], s2 = v ? rend2[v - 1] : 0;

    float4 accP = make_float4(0.f, 0.f, 0.f, 0.f);
    {
        int p = s0;
        for (; p + 1 < e0; p += 2) {
            int sa = adj_jj[p], sb = adj_jj[p + 1];
            float wa = sc_pre[sa], wb = sc_pre[sb];
            float4 ha = load_h16(cur, sa, c);
            float4 hb = load_h16(cur, sb, c);
            accP.x += ha.x * wa + hb.x * wb; accP.y += ha.y * wa + hb.y * wb;
            accP.z += ha.z * wa + hb.z * wb; accP.w += ha.w * wa + hb.w * wb;
        }
        if (p < e0) {
            int sa = adj_jj[p];
            float wa = sc_pre[sa];
            float4 ha = load_h16(cur, sa, c);
            accP.x += ha.x * wa; accP.y += ha.y * wa; accP.z += ha.z * wa; accP.w += ha.w * wa;
        }
    }
    float4 accN = make_float4(0.f, 0.f, 0.f, 0.f);
    {
        int p = s1;
        for (; p + 1 < e1; p += 2) {
            int sa = adj_jj[p], sb = adj_jj[p + 1];
            float wa = sc_nxt[sa], wb = sc_nxt[sb];
            float4 ha = load_h16(cur, sa, c);
            float4 hb = load_h16(cur, sb, c);
            accN.x += ha.x * wa + hb.x * wb; accN.y += ha.y * wa + hb.y * wb;
            accN.z += ha.z * wa + hb.z * wb; accN.w += ha.w * wa + hb.w * wb;
        }
        if (p < e1) {
            int sa = adj_jj[p];
            float wa = sc_nxt[sa];
            float4 ha = load_h16(cur, sa, c);
            accN.x += ha.x * wa; accN.y += ha.y * wa; accN.z += ha.z * wa; accN.w += ha.w * wa;
        }
    }
    float4 accS = make_float4(0.f, 0.f, 0.f, 0.f);
    for (int p = s2; p < e2; ++p) {
        int sa = adj_proc[p].x;
        float4 ha = ((const float4*)(hwk + (size_t)sa * 16))[c];
        accS.x += ha.x; accS.y += ha.y; accS.z += ha.z; accS.w += ha.w;
    }

    int d0 = e0 - s0, d1 = e1 - s1, d2 = e2 - s2;
    float rp = rsqrtf((float)(d0 < 1 ? 1 : d0));
    float rn = rsqrtf((float)(d1 < 1 ? 1 : d1));
    float ri = 1.0f / (float)(d2 < 1 ? 1 : d2);
    accP.x *= rp; accP.y *= rp; accP.z *= rp; accP.w *= rp;
    accN.x *= rn; accN.y *= rn; accN.z *= rn; accN.w *= rn;
    accS.x *= ri; accS.y *= ri; accS.z *= ri; accS.w *= ri;

    float o[4];
#pragma unroll
    for (int j = 0; j < 4; ++j) o[j] = bs[c * 4 + j];
    mm_accum(WpS, accP, c, o);
    mm_accum(WnS, accN, c, o);
    mm_accum(WngS, accS, c, o);
    float4 hself = load_h16(cur, v, c);
    mm_accum(WsfS, hself, c, o);

    if (!FINAL) {
        uint2* dst = (uint2*)(out + (size_t)v * 16 + c * 4);
        *dst = make_uint2(pack_h2(o[0], o[1]), pack_h2(o[2], o[3]));
    } else {
        for (int p = s2; p < e2; ++p) {
            int2 pr = adj_proc[p];
            float4 wv = ((const float4*)(hwk + (size_t)pr.x * 16))[c];
            float d = o[0] * wv.x + o[1] * wv.y + o[2] * wv.z + o[3] * wv.w;
            d += __shfl_xor(d, 1, 4);
            d += __shfl_xor(d, 2, 4);
            if (c == 0) scores[pr.y] = d;
        }
    }
}

extern "C" void kernel_launch(void* const* d_in, const int* in_sizes, int n_in,
                              void* d_out, int out_size, void* d_ws, size_t ws_size,
                              hipStream_t stream) {
    const float* job_feat     = (const float*)d_in[0];
    const float* worker_feat  = (const float*)d_in[1];
    const int*   pre_src      = (const int*)d_in[2];
    const int*   pre_dst      = (const int*)d_in[3];
    const int*   nxt_src      = (const int*)d_in[4];
    const int*   nxt_dst      = (const int*)d_in[5];
    const int*   proc_src     = (const int*)d_in[6];
    const int*   proc_dst     = (const int*)d_in[7];
    const float* W_emb_job    = (const float*)d_in[8];
    const float* b_emb_job    = (const float*)d_in[9];
    const float* W_emb_worker = (const float*)d_in[10];
    const float* b_emb_worker = (const float*)d_in[11];
    const float* W_pre        = (const float*)d_in[12];
    const float* b_pre        = (const float*)d_in[13];
    const float* W_nxt        = (const float*)d_in[14];
    const float* b_nxt        = (const float*)d_in[15];
    const float* W_self       = (const float*)d_in[16];
    const float* W_neigh      = (const float*)d_in[17];
    const float* b_sage       = (const float*)d_in[18];
    float* out = (float*)d_out;

    // Workspace (~125 MB). fp16 h buffers + hw alias the dead bucket region.
    float* ws = (float*)d_ws;
    __half* h16A = (__half*)ws;                         // 8M halfs = 4M u32
    __half* h16B = (__half*)(ws + 4000000);             // 8M halfs = 4M u32
    float*  hw   = ws + 8000000;                        //   800,000 f
    unsigned* jjb = (unsigned*)ws;                      // 124*67584 = 8,380,416 u32
    int2*  procb  = (int2*)(ws + 8380416);              // 62*34000 int2
    unsigned short* srcb = (unsigned short*)(ws + 12596416); // 124*67584 u16
    int*   off  = (int*)(ws + 16800000);                // 1,500,000 (row ends)
    int*   gcur = off + 3 * N_JOB;                      // 512
    int*   adj_jj = gcur + 512;                         // 8,000,000
    int2*  adj_proc = (int2*)(adj_jj + 8000000);        // 2,000,000 int2
    float* sc_pre = (float*)(adj_proc + 2000000);       // 500,000
    float* sc_nxt = sc_pre + N_JOB;                     // 500,000

    cursor_init<<<1, 512, 0, stream>>>(gcur);
    partition_kernel<<<2 * NB_PRE + NB_PROC, 256, 0, stream>>>(
        pre_src, pre_dst, nxt_src, nxt_dst, proc_src, proc_dst,
        gcur, jjb, procb, srcb);
    csr_build<<<3 * NWIN, 256, 0, stream>>>(jjb, procb, gcur, off, adj_jj, adj_proc);
    outdeg_build<<<2 * NWIN, 256, 0, stream>>>(srcb, gcur, sc_pre, sc_nxt);

    embed_kernel<7, true><<<(N_JOB + 255) / 256, 256, 0, stream>>>(
        job_feat, W_emb_job, b_emb_job, h16A, N_JOB);
    embed_kernel<3, false><<<(N_WORKER + 255) / 256, 256, 0, stream>>>(
        worker_feat, W_emb_worker, b_emb_worker, hw, N_WORKER);

    const int GGRID = (4 * N_JOB + 255) / 256;
    gather_layer<false><<<GGRID, 256, 0, stream>>>(
        h16A, hw, adj_jj, adj_proc, off, sc_pre, sc_nxt,
        W_pre, W_nxt, W_neigh, W_self, b_pre, b_nxt, b_sage, h16B, nullptr);
    gather_layer<true><<<GGRID, 256, 0, stream>>>(
        h16B, hw, adj_jj, adj_proc, off, sc_pre, sc_nxt,
        W_pre, W_nxt, W_neigh, W_self, b_pre, b_nxt, b_sage, nullptr, out);
}